// Round 9
// baseline (660.737 us; speedup 1.0000x reference)
//
#include <hip/hip_runtime.h>
#include <stdint.h>
#include <math.h>

#define N_ANCH   1000000
#define PRE_K    6000
#define POST_K   1000
#define WORDS    94            // ceil(6000/64) bit-words per row
#define WPAD     96            // padded row stride (u64) -> 768B, 16B-aligned
#define ROWS     6016          // WORDS*64
#define W_IMG    1333.0f
#define H_IMG    800.0f
#define NBLK     256           // histogram blocks (x1024 threads), partial-based

// radix sort config (single block)
#define NS       7168
#define TILES    112
#define TPW      7
#define PASSES   13            // 13 x 4 bits = 52 = 32-bit key + 20-bit idx

// ws layout (bytes). keys/maskT alias (keys dead after k_compact; maskT written
// by k_iou later). part1 aliases row-major mask (part1 dead after k_score).
#define OFF_KEYS   0x000000u   // u32[1e6]        (4,000,000)
#define OFF_MASKT  0x000000u   // u64[94*6016]    (4,524,032) -> 0x450800
#define OFF_PART2  0x451000u   // u32[NBLK*256]   (256 KiB)   -> 0x491000
#define OFF_CTRL   0x491000u   // [0]=count [1]=T20 [2]=c [3]=base [4],[5]=done
#define OFF_CAND   0x491100u   // u64[NS] 56 KiB
#define OFF_BOXES  0x4A0000u   // float4[6016]
#define OFF_VALID  0x4B8000u   // u32[6016]
#define OFF_MASK   0x4C0000u   // u64[6016*WPAD] row-major -> 0x928000 (~9.6MB)
#define OFF_PART1  0x4C0000u   // u32[NBLK*4096] 4 MiB, ALIASES mask (disjoint life)

#define AS1 __attribute__((address_space(1)))
#define AS3 __attribute__((address_space(3)))

__device__ __forceinline__ float ref_exp(float v) {
  return (float)exp((double)v);   // correctly-rounded f32 exp via double
}

__device__ __forceinline__ void decode_box(float ax, float ay, float az, float aw,
                                           float dx, float dy, float dz, float dw,
                                           float& x1, float& y1, float& x2, float& y2,
                                           bool& valid) {
  // bit-exact replica of reference fp32 op order (no FMA contraction)
  float wa = __fsub_rn(az, ax);
  float ha = __fsub_rn(aw, ay);
  float xa = __fadd_rn(ax, __fmul_rn(0.5f, wa));
  float ya = __fadd_rn(ay, __fmul_rn(0.5f, ha));
  float x  = __fadd_rn(__fmul_rn(dx, wa), xa);
  float y  = __fadd_rn(__fmul_rn(dy, ha), ya);
  float w  = __fmul_rn(ref_exp(dz), wa);
  float h  = __fmul_rn(ref_exp(dw), ha);
  float hw = __fmul_rn(0.5f, w);
  float hh = __fmul_rn(0.5f, h);
  x1 = fminf(fmaxf(__fsub_rn(x, hw), 0.0f), W_IMG - 1.0f);
  y1 = fminf(fmaxf(__fsub_rn(y, hh), 0.0f), H_IMG - 1.0f);
  x2 = fminf(fmaxf(__fadd_rn(x, hw), 0.0f), W_IMG - 1.0f);
  y2 = fminf(fmaxf(__fadd_rn(y, hh), 0.0f), H_IMG - 1.0f);
  valid = (__fsub_rn(x2, x1) >= 16.0f) && (__fsub_rn(y2, y1) >= 16.0f);
}

__device__ __forceinline__ uint32_t wave_iscan(uint32_t x, int lane) {
  #pragma unroll
  for (int off = 1; off < 64; off <<= 1) {
    uint32_t u = __shfl_up(x, off, 64);
    if (lane >= off) x += u;
  }
  return x;
}

// ---- K1: decode + key + LDS 12-bit hist -> per-block partials; last block: coarse cut ----
__global__ void __launch_bounds__(1024) k_score(const float4* __restrict__ anchors,
                                                const float4* __restrict__ deltas,
                                                const float*  __restrict__ logits,
                                                uint32_t* __restrict__ keys,
                                                uint32_t* __restrict__ part1,
                                                uint32_t* __restrict__ ctrl) {
  __shared__ uint32_t lh[4096];
  __shared__ uint32_t amLast;
  int tid = threadIdx.x;
  int lane = tid & 63;
  for (int b = tid; b < 4096; b += 1024) lh[b] = 0u;
  __syncthreads();
  for (int i = blockIdx.x * 1024 + tid; i < N_ANCH; i += NBLK * 1024) {
    float4 a = anchors[i];
    float4 d = deltas[i];
    float x1, y1, x2, y2; bool valid;
    decode_box(a.x, a.y, a.z, a.w, d.x, d.y, d.z, d.w, x1, y1, x2, y2, valid);
    uint32_t kd;
    if (valid) {
      double xd = (double)logits[i];
      float s = (float)(1.0 / (1.0 + exp(-xd)));
      uint32_t u = __float_as_uint(s);
      kd = 0x7FFFFFFFu & ~u;        // descending-score -> ascending key
    } else {
      kd = 0xFF800000u;             // -inf key (bin 0xFF8)
    }
    keys[i] = kd;
    uint64_t invb = __ballot(!valid);   // aggregate the hot invalid bin
    if (valid) {
      atomicAdd(&lh[kd >> 20], 1u);
    } else if ((invb & ((1ull << lane) - 1ull)) == 0ull) {
      atomicAdd(&lh[0xFF8u], (uint32_t)__popcll((unsigned long long)invb));
    }
  }
  __syncthreads();
  for (int b = tid; b < 4096; b += 1024)
    part1[blockIdx.x * 4096 + b] = lh[b];
  __threadfence();
  if (tid == 0) amLast = (atomicAdd(&ctrl[4], 1u) == NBLK - 1) ? 1u : 0u;
  __syncthreads();
  if (!amLast) return;
  __threadfence();
  // ---- findcut1 (this block only) ----
  __shared__ uint32_t part[1024];
  int t = tid;
  uint4 s4 = make_uint4(0u, 0u, 0u, 0u);     // thread t owns bins 4t..4t+3
  const uint4* p4 = (const uint4*)part1;
  for (int k = 0; k < NBLK; k++) {
    uint4 q = p4[k * 1024 + t];
    s4.x += q.x; s4.y += q.y; s4.z += q.z; s4.w += q.w;
  }
  uint32_t tot = s4.x + s4.y + s4.z + s4.w;
  part[t] = tot;
  __syncthreads();
  uint32_t inc = tot;
  for (int off = 1; off < 1024; off <<= 1) {
    uint32_t u = (t >= off) ? part[t - off] : 0u;
    __syncthreads();
    inc += u;
    part[t] = inc;
    __syncthreads();
  }
  uint32_t ex = inc - tot;
  if (ex < PRE_K && inc >= PRE_K) {
    uint32_t run = ex;
    uint32_t binv[4] = { s4.x, s4.y, s4.z, s4.w };
    for (int b = 0; b < 4; b++) {
      if (run + binv[b] >= PRE_K) { ctrl[2] = 4 * t + b; ctrl[3] = run; break; }
      run += binv[b];
    }
  }
  if (t == 1023 && inc < PRE_K) { ctrl[2] = 4095u; ctrl[3] = inc; }
}

// ---- K2: refine next 8 bits in coarse bin (partials); last block finds T20 ----
__global__ void __launch_bounds__(1024) k_hist2(const uint32_t* __restrict__ keys,
                                                uint32_t* __restrict__ ctrl,
                                                uint32_t* __restrict__ part2) {
  __shared__ uint32_t lh[256];
  __shared__ uint32_t amLast;
  int tid = threadIdx.x;
  if (tid < 256) lh[tid] = 0u;
  __syncthreads();
  uint32_t c = ctrl[2];
  for (int i = blockIdx.x * 1024 + tid; i < N_ANCH; i += NBLK * 1024) {
    uint32_t k = keys[i];
    if ((k >> 20) == c) atomicAdd(&lh[(k >> 12) & 0xFFu], 1u);
  }
  __syncthreads();
  if (tid < 256) part2[blockIdx.x * 256 + tid] = lh[tid];
  __threadfence();
  if (tid == 0) amLast = (atomicAdd(&ctrl[5], 1u) == NBLK - 1) ? 1u : 0u;
  __syncthreads();
  if (!amLast) return;
  __threadfence();
  if (tid < 64) {
    int lane = tid;
    uint32_t b0 = 0, b1 = 0, b2 = 0, b3 = 0;
    for (int k = 0; k < NBLK; k++) {
      const uint32_t* p = part2 + k * 256 + 4 * lane;
      b0 += p[0]; b1 += p[1]; b2 += p[2]; b3 += p[3];
    }
    uint32_t tot = b0 + b1 + b2 + b3;
    uint32_t inc = wave_iscan(tot, lane);
    uint32_t base = ctrl[3];
    uint32_t ex = inc - tot;
    if (base + ex < PRE_K && base + inc >= PRE_K) {
      uint32_t run = base + ex;
      uint32_t binv[4] = { b0, b1, b2, b3 };
      for (int b = 0; b < 4; b++) {
        if (run + binv[b] >= PRE_K) { ctrl[1] = (c << 8) | (uint32_t)(4 * lane + b); break; }
        run += binv[b];
      }
    }
    if (lane == 63 && base + inc < PRE_K) ctrl[1] = 0xFFFFFu;  // take everything
  }
}

// ---- K3: compact candidates (key prefix <= T), wave-aggregated atomic ----
__global__ void k_compact(const uint32_t* __restrict__ keys,
                          const uint32_t* __restrict__ ctrl,
                          uint32_t* __restrict__ cnt,
                          uint64_t* __restrict__ cand) {
  int i = blockIdx.x * blockDim.x + threadIdx.x;
  uint32_t T = ctrl[1];
  bool pass = (i < N_ANCH) && ((keys[i] >> 12) <= T);
  uint64_t m = __ballot(pass);
  if (pass) {
    int lane = threadIdx.x & 63;
    int leader = __ffsll((unsigned long long)m) - 1;
    uint32_t base = 0;
    if (lane == leader) base = atomicAdd(cnt, (uint32_t)__popcll((unsigned long long)m));
    base = (uint32_t)__shfl((int)base, leader);
    uint32_t pos = (uint32_t)__popcll((unsigned long long)(m & ((1ull << lane) - 1ull)));
    uint32_t p = base + pos;
    if (p < NS) cand[p] = ((uint64_t)keys[i] << 20) | (uint32_t)i;  // 52-bit packed
  }
}

// ---- K4: single-block LSD radix sort (4-bit x 13) + gather/decode epilogue ----
__global__ void __launch_bounds__(1024) k_sortgather(
    const uint32_t* __restrict__ ctrl,
    const uint64_t* __restrict__ cand,
    const float4* __restrict__ anchors,
    const float4* __restrict__ deltas,
    float4* __restrict__ boxes,
    uint32_t* __restrict__ valid) {
  __shared__ uint64_t buf[NS];            // 56 KiB
  __shared__ uint32_t hist[16 * TILES];   // 7 KiB
  __shared__ uint32_t dtot[16];
  __shared__ uint32_t dbase[16];
  __shared__ uint32_t skipf;
  int tid = threadIdx.x;
  int wave = tid >> 6, lane = tid & 63;
  uint32_t M = ctrl[0]; if (M > NS) M = NS;
  uint32_t T = ctrl[1];
  uint64_t pad = (T >= 0xFFFFFu) ? 0xFFFFFFFFFFFFFull
                                 : ((((uint64_t)T + 1) << 32) | 0xFFFFFFFFull);
  for (int i = tid; i < NS; i += 1024)
    buf[i] = (i < (int)M) ? cand[i] : pad;
  __syncthreads();
  uint64_t lmask_lt = (1ull << lane) - 1ull;

  for (int p = 0; p < PASSES; p++) {
    int shift = 4 * p;
    for (int i = tid; i < 16 * TILES; i += 1024) hist[i] = 0u;
    uint64_t v[TPW]; int dg[TPW]; int rk[TPW];
    #pragma unroll
    for (int k = 0; k < TPW; k++)
      v[k] = buf[(wave * TPW + k) * 64 + lane];
    __syncthreads();
    #pragma unroll
    for (int k = 0; k < TPW; k++) {
      int d = (int)((v[k] >> shift) & 0xF);
      uint64_t m = ~0ull;
      #pragma unroll
      for (int b = 0; b < 4; b++) {
        uint64_t bal = __ballot((d >> b) & 1);
        m &= ((d >> b) & 1) ? bal : ~bal;
      }
      int r = (int)__popcll((unsigned long long)(m & lmask_lt));
      dg[k] = d; rk[k] = r;
      if (r == 0) hist[d * TILES + wave * TPW + k] = (uint32_t)__popcll((unsigned long long)m);
    }
    __syncthreads();
    {
      int d = wave;
      uint32_t c0 = hist[d * TILES + lane];
      uint32_t c1 = (lane < TILES - 64) ? hist[d * TILES + 64 + lane] : 0u;
      uint32_t s0 = wave_iscan(c0, lane);
      uint32_t T0 = (uint32_t)__shfl((int)s0, 63, 64);
      uint32_t s1 = wave_iscan(c1, lane);
      uint32_t T1 = (uint32_t)__shfl((int)s1, 63, 64);
      hist[d * TILES + lane] = s0 - c0;
      if (lane < TILES - 64) hist[d * TILES + 64 + lane] = T0 + (s1 - c1);
      if (lane == 0) dtot[d] = T0 + T1;
    }
    __syncthreads();
    if (wave == 0) {
      uint32_t x = (lane < 16) ? dtot[lane] : 0u;
      uint32_t xs = wave_iscan(x, lane);
      if (lane < 16) dbase[lane] = xs - x;
      if (lane == 0) skipf = 0u;
      if (lane < 16 && x == NS) skipf = 1u;
    }
    __syncthreads();
    if (!skipf) {
      #pragma unroll
      for (int k = 0; k < TPW; k++) {
        uint32_t dst = dbase[dg[k]] + hist[dg[k] * TILES + wave * TPW + k] + (uint32_t)rk[k];
        buf[dst] = v[k];
      }
    }
    __syncthreads();
  }

  for (int r = tid; r < ROWS; r += 1024) {
    if (r >= PRE_K) { boxes[r] = make_float4(0.f, 0.f, 0.f, 0.f); valid[r] = 0u; continue; }
    uint64_t kk = buf[r];
    uint32_t kd = (uint32_t)(kk >> 20);
    if (kk >= pad || kd >= 0xFF800000u) {
      boxes[r] = make_float4(0.f, 0.f, 0.f, 0.f); valid[r] = 0u; continue;
    }
    uint32_t idx = (uint32_t)(kk & 0xFFFFFu);
    float4 a = anchors[idx];
    float4 d = deltas[idx];
    float x1, y1, x2, y2; bool vv;
    decode_box(a.x, a.y, a.z, a.w, d.x, d.y, d.z, d.w, x1, y1, x2, y2, vv);
    boxes[r] = make_float4(x1, y1, x2, y2);
    valid[r] = 1u;
  }
}

// ---- K5: IoU bitmask, DUAL layout: row-major + transposed ----
__global__ void __launch_bounds__(64) k_iou(const float4* __restrict__ boxes,
                                            uint64_t* __restrict__ mask,
                                            uint64_t* __restrict__ maskT) {
  int by = blockIdx.y, bx = blockIdx.x;
  if (bx < by) return;
  __shared__ float4 cb[64];
  int t = threadIdx.x;
  cb[t] = boxes[bx * 64 + t];
  __syncthreads();
  int i = by * 64 + t;
  float4 b = boxes[i];
  float ax1 = b.x, ay1 = b.y, ax2 = b.z, ay2 = b.w;
  float areaA = __fmul_rn(__fsub_rn(ax2, ax1), __fsub_rn(ay2, ay1));
  uint64_t bits = 0;
  for (int c = 0; c < 64; c++) {
    float4 o = cb[c];
    float areaB = __fmul_rn(__fsub_rn(o.z, o.x), __fsub_rn(o.w, o.y));
    float ix1 = fmaxf(ax1, o.x), iy1 = fmaxf(ay1, o.y);
    float ix2 = fminf(ax2, o.z), iy2 = fminf(ay2, o.w);
    float iw = fmaxf(__fsub_rn(ix2, ix1), 0.0f);
    float ih = fmaxf(__fsub_rn(iy2, iy1), 0.0f);
    float inter = __fmul_rn(iw, ih);
    float uni = __fsub_rn(__fadd_rn(areaA, areaB), inter);
    bool sup = (uni > 0.0f) && (__fdiv_rn(inter, uni) > 0.7f);
    bits |= ((uint64_t)sup) << c;
  }
  mask[(size_t)i * WPAD + bx] = bits;          // row-major (fold DMA source)
  maskT[(size_t)bx * ROWS + i] = bits;         // transposed (column DMA source)
}

// wave-uniform 64-bit broadcast via v_readlane
__device__ __forceinline__ uint64_t bcast64(uint64_t v, int lane) {
  uint32_t lo = (uint32_t)__builtin_amdgcn_readlane((int)(uint32_t)v, lane);
  uint32_t hi = (uint32_t)__builtin_amdgcn_readlane((int)(uint32_t)(v >> 32), lane);
  return ((uint64_t)hi << 32) | lo;
}

#define F_PAD 24   // fold DMA instructions per group (padded -> static vmcnt)
// vmcnt immediates (gfx9 encoding: vm[3:0]=b3:0, exp=b6:4, lgkm=b11:8, vm[5:4]=b15:14)
#define WAITCNT_VM0   0x0F70u   // vmcnt(0)
#define WAITCNT_VM27  0x4F7Bu   // vmcnt(27) = F_PAD + 3 newer allowed

// one mask row (768B) -> LDS stage row: lanes 0..47 x 16B
__device__ __forceinline__ void dma_row(const uint64_t* rowp, uint64_t* ldsrow, int lane) {
  if (lane < 48)
    __builtin_amdgcn_global_load_lds((const AS1 uint32_t*)(rowp + 2 * lane),
                                     (AS3 uint32_t*)ldsrow, 16, 0, 0);
}
// one column vector (64 u64, 512B): lanes 0..31 x 16B
__device__ __forceinline__ void dma_col(const uint64_t* src, uint64_t* lds, int lane) {
  if (lane < 32)
    __builtin_amdgcn_global_load_lds((const AS1 uint32_t*)(src + 2 * lane),
                                     (AS3 uint32_t*)lds, 16, 0, 0);
}
// 64 u32 validity flags (256B)
__device__ __forceinline__ void dma_vf(const uint32_t* src, uint32_t* lds, int lane) {
  __builtin_amdgcn_global_load_lds((const AS1 uint32_t*)(src + lane),
                                   (AS3 uint32_t*)lds, 4, 0, 0);
}

// OR staged rows into r0/r1 (clamped index + idempotent OR -> no predication)
__device__ __forceinline__ void commit_rows(const uint64_t (*sbuf)[WPAD], int n,
                                            int w0, int w1, uint64_t& r0, uint64_t& r1) {
  if (n <= 0) return;
  int w1s = (w1 < WORDS) ? w1 : 0;
  uint64_t a0 = 0, a1 = 0;
  for (int jb = 0; jb < n; jb += 8) {
    #pragma unroll
    for (int ji = 0; ji < 8; ji++) {
      int js = jb + ji; js = (js < n) ? js : (n - 1);
      a0 |= sbuf[js][w0];
      a1 |= sbuf[js][w1s];
    }
  }
  r0 |= a0;
  if (w1 < WORDS) r1 |= a1;
}

// ---- K6: sequential NMS; all-DMA + one-group lookahead (cur_next via colv2) ----
// Group g's kept-row folds are needed only from group g+2 (cur_next covers g+1),
// so the wait at group g is vmcnt(27): lets fold(g-1)[24]+cols[3] stay in flight
// and targets DMAs issued a FULL GROUP earlier -> near-zero stall.
__global__ void __launch_bounds__(64, 1) k_nms(const uint64_t* __restrict__ mask,
                                               const uint64_t* __restrict__ maskT,
                                               const float4* __restrict__ boxes,
                                               const uint32_t* __restrict__ valid,
                                               float* __restrict__ out) {
  __shared__ uint64_t fstage[2][F_PAD][WPAD] __attribute__((aligned(16)));  // 36 KiB
  __shared__ uint64_t cstage[2][2][64] __attribute__((aligned(16)));        // [buf][colv|colv2]
  __shared__ uint32_t vstage[2][64] __attribute__((aligned(16)));
  __shared__ uint32_t list[1024];
  int lane = threadIdx.x;
  int w0 = lane, w1 = lane + 64;
  uint64_t r0 = 0, r1 = 0;      // removed words (folds <= g-2)
  uint64_t cur_next = 0;        // word-g bits from rows kept in group g-1
  int cnt = 0, pendA = 0, pendB = 0;
  // preload col/colv2/vf for groups 0 and 1
  dma_col(maskT + (size_t)0 * ROWS + 0,  &cstage[0][0][0], lane);
  dma_col(maskT + (size_t)1 * ROWS + 0,  &cstage[0][1][0], lane);
  dma_vf (valid + 0,                     &vstage[0][0], lane);
  dma_col(maskT + (size_t)1 * ROWS + 64, &cstage[1][0][0], lane);
  dma_col(maskT + (size_t)2 * ROWS + 64, &cstage[1][1][0], lane);
  dma_vf (valid + 64,                    &vstage[1][0], lane);
  __builtin_amdgcn_s_waitcnt(WAITCNT_VM0);
  for (int g = 0; g < WORDS; g++) {
    int base = g * 64;
    int ping = g & 1;
    if (g >= 2) {
      __builtin_amdgcn_s_waitcnt(WAITCNT_VM27);     // fold(g-2)+cols(g) landed
      commit_rows(fstage[ping], pendA, w0, w1, r0, r1);
    }
    uint64_t colv  = cstage[ping][0][lane];         // row (base+lane)'s word g
    uint64_t colv2 = cstage[ping][1][lane];         // row (base+lane)'s word g+1
    uint32_t vf    = vstage[ping][lane];
    uint64_t cur = ((g < 64) ? bcast64(r0, g) : bcast64(r1, g - 64)) | cur_next;
    uint64_t vmask = __ballot(vf != 0u);
    uint64_t alive = vmask & ~cur;
    uint64_t keptmask = 0;
    while (alive) {                                 // serial decision chain
      int r = __ffsll((unsigned long long)alive) - 1;
      keptmask |= 1ull << r;
      if (lane == 0) list[cnt] = (uint32_t)(base + r);
      cnt++;
      if (cnt >= POST_K) break;
      alive &= ~bcast64(colv, r);                   // in-group suppression
      alive &= ~(1ull << r);
    }
    if (cnt >= POST_K) break;
    // cur_next for g+1: OR of colv2 over kept lanes (butterfly, off serial chain)
    {
      uint64_t v = ((keptmask >> lane) & 1ull) ? colv2 : 0ull;
      #pragma unroll
      for (int off = 32; off >= 1; off >>= 1)
        v |= (uint64_t)__shfl_xor((unsigned long long)v, off, 64);
      cur_next = v;
    }
    // issue fold DMAs for kept rows, padded to exactly F_PAD instructions
    uint64_t kml = keptmask;
    int slot = 0;
    while (kml) {
      if (slot == F_PAD) {                          // rare overflow: drain in place
        __builtin_amdgcn_s_waitcnt(WAITCNT_VM0);
        commit_rows(fstage[ping], F_PAD, w0, w1, r0, r1);
        slot = 0;
      }
      int r = __ffsll((unsigned long long)kml) - 1;
      kml &= kml - 1;
      dma_row(mask + (size_t)(base + r) * WPAD, &fstage[ping][slot][0], lane);
      slot++;
    }
    for (int s = slot; s < F_PAD; s++)              // dummies keep count static
      dma_row(mask + (size_t)base * WPAD, &fstage[ping][s][0], lane);
    pendA = pendB; pendB = slot;
    // issue col/colv2/vf for g+2 (clamped dummy at the tail)
    int gg = (g + 2 < WORDS) ? (g + 2) : (WORDS - 1);
    size_t rb = (size_t)gg * 64;
    dma_col(maskT + (size_t)gg * ROWS + rb,       &cstage[ping][0][0], lane);
    dma_col(maskT + (size_t)(gg + 1) * ROWS + rb, &cstage[ping][1][0], lane); // word 94 read is in-ws garbage, never used
    dma_vf (valid + rb, &vstage[ping][0], lane);
  }
  __syncthreads();
  float4* outv = (float4*)out;
  for (int k = lane; k < POST_K; k += 64)
    outv[k] = (k < cnt) ? boxes[list[k]] : make_float4(0.f, 0.f, 0.f, 0.f);
}

extern "C" void kernel_launch(void* const* d_in, const int* in_sizes, int n_in,
                              void* d_out, int out_size, void* d_ws, size_t ws_size,
                              hipStream_t stream) {
  const float4* anchors = (const float4*)d_in[1];
  const float4* deltas  = (const float4*)d_in[2];
  const float*  logits  = (const float*)d_in[3];
  char* w = (char*)d_ws;
  uint32_t* keys  = (uint32_t*)(w + OFF_KEYS);
  uint64_t* maskT = (uint64_t*)(w + OFF_MASKT);
  uint32_t* part1 = (uint32_t*)(w + OFF_PART1);
  uint32_t* part2 = (uint32_t*)(w + OFF_PART2);
  uint32_t* ctrl  = (uint32_t*)(w + OFF_CTRL);
  uint64_t* cand  = (uint64_t*)(w + OFF_CAND);
  float4*   boxes = (float4*)(w + OFF_BOXES);
  uint32_t* valid = (uint32_t*)(w + OFF_VALID);
  uint64_t* mask  = (uint64_t*)(w + OFF_MASK);
  float*    out   = (float*)d_out;

  hipMemsetAsync(w + OFF_CTRL, 0, 256, stream);   // counters only

  k_score<<<NBLK, 1024, 0, stream>>>(anchors, deltas, logits, keys, part1, ctrl);
  k_hist2<<<NBLK, 1024, 0, stream>>>(keys, ctrl, part2);
  k_compact<<<(N_ANCH + 255) / 256, 256, 0, stream>>>(keys, ctrl, &ctrl[0], cand);
  k_sortgather<<<1, 1024, 0, stream>>>(ctrl, cand, anchors, deltas, boxes, valid);
  k_iou<<<dim3(WORDS, WORDS), 64, 0, stream>>>(boxes, mask, maskT);
  k_nms<<<1, 64, 0, stream>>>(mask, maskT, boxes, valid, out);
}

// Round 10
// 456.016 us; speedup vs baseline: 1.4489x; 1.4489x over previous
//
#include <hip/hip_runtime.h>
#include <stdint.h>
#include <math.h>

#define N_ANCH   1000000
#define PRE_K    6000
#define POST_K   1000
#define WORDS    94            // ceil(6000/64) -> 6016 bit columns
#define ROWS     6016          // WORDS*64
#define W_IMG    1333.0f
#define H_IMG    800.0f
#define NBLK1    64            // histogram blocks (x1024 threads)

// radix sort config (single block)
#define NS       7168          // sort capacity (112 tiles of 64)
#define TILES    112
#define TPW      7             // tiles per wave (16 waves)
#define PASSES   13            // 13 x 4 bits = 52 = 32-bit key + 20-bit idx

// ws layout (bytes)  (R6-proven)
#define OFF_KEYS   0x000000u   // u32[1e6]
#define OFF_PART1  0x400000u   // u32[NBLK1*4096] = 1 MiB
#define OFF_PART2  0x500000u   // u32[NBLK1*256]  = 64 KiB
#define OFF_CTRL   0x510000u   // [0]=count [1]=T20 [2]=coarse c [3]=base [4],[5]=done ctrs
#define OFF_CAND   0x510100u   // u64[NS] 56 KiB
#define OFF_BOXES  0x51F000u   // float4[6016]
#define OFF_VALID  0x537000u   // u32[6016]
#define OFF_MASK   0x540000u   // u64[6016*94] row-major: mask[row*WORDS + w]

__device__ __forceinline__ float ref_exp(float v) {
  return (float)exp((double)v);   // correctly-rounded f32 exp via double
}

__device__ __forceinline__ void decode_box(float ax, float ay, float az, float aw,
                                           float dx, float dy, float dz, float dw,
                                           float& x1, float& y1, float& x2, float& y2,
                                           bool& valid) {
  // bit-exact replica of reference fp32 op order (no FMA contraction)
  float wa = __fsub_rn(az, ax);
  float ha = __fsub_rn(aw, ay);
  float xa = __fadd_rn(ax, __fmul_rn(0.5f, wa));
  float ya = __fadd_rn(ay, __fmul_rn(0.5f, ha));
  float x  = __fadd_rn(__fmul_rn(dx, wa), xa);
  float y  = __fadd_rn(__fmul_rn(dy, ha), ya);
  float w  = __fmul_rn(ref_exp(dz), wa);
  float h  = __fmul_rn(ref_exp(dw), ha);
  float hw = __fmul_rn(0.5f, w);
  float hh = __fmul_rn(0.5f, h);
  x1 = fminf(fmaxf(__fsub_rn(x, hw), 0.0f), W_IMG - 1.0f);
  y1 = fminf(fmaxf(__fsub_rn(y, hh), 0.0f), H_IMG - 1.0f);
  x2 = fminf(fmaxf(__fadd_rn(x, hw), 0.0f), W_IMG - 1.0f);
  y2 = fminf(fmaxf(__fadd_rn(y, hh), 0.0f), H_IMG - 1.0f);
  valid = (__fsub_rn(x2, x1) >= 16.0f) && (__fsub_rn(y2, y1) >= 16.0f);
}

__device__ __forceinline__ uint32_t wave_iscan(uint32_t x, int lane) {
  #pragma unroll
  for (int off = 1; off < 64; off <<= 1) {
    uint32_t u = __shfl_up(x, off, 64);
    if (lane >= off) x += u;
  }
  return x;
}

// ---- K1: decode + score key + 12-bit LDS histogram; last block finds coarse cut ----
__global__ void __launch_bounds__(1024) k_score(const float4* __restrict__ anchors,
                                                const float4* __restrict__ deltas,
                                                const float*  __restrict__ logits,
                                                uint32_t* __restrict__ keys,
                                                uint32_t* __restrict__ part1,
                                                uint32_t* __restrict__ ctrl) {
  __shared__ uint32_t lh[4096];
  __shared__ uint32_t amLast;
  int tid = threadIdx.x;
  int lane = tid & 63;
  for (int b = tid; b < 4096; b += 1024) lh[b] = 0u;
  __syncthreads();
  for (int i = blockIdx.x * 1024 + tid; i < N_ANCH; i += NBLK1 * 1024) {
    float4 a = anchors[i];
    float4 d = deltas[i];
    float x1, y1, x2, y2; bool valid;
    decode_box(a.x, a.y, a.z, a.w, d.x, d.y, d.z, d.w, x1, y1, x2, y2, valid);
    uint32_t kd;
    if (valid) {
      double xd = (double)logits[i];
      float s = (float)(1.0 / (1.0 + exp(-xd)));
      uint32_t u = __float_as_uint(s);
      kd = 0x7FFFFFFFu & ~u;        // descending-score -> ascending key
    } else {
      kd = 0xFF800000u;             // -inf key (bin 0xFF8)
    }
    keys[i] = kd;
    // ballot-aggregate the hot invalid bin: one LDS atomic per wave
    uint64_t invb = __ballot(!valid);
    if (valid) {
      atomicAdd(&lh[kd >> 20], 1u);
    } else if ((invb & ((1ull << lane) - 1ull)) == 0ull) {
      atomicAdd(&lh[0xFF8u], (uint32_t)__popcll((unsigned long long)invb));
    }
  }
  __syncthreads();
  for (int b = tid; b < 4096; b += 1024)
    part1[blockIdx.x * 4096 + b] = lh[b];
  __threadfence();
  if (tid == 0) amLast = (atomicAdd(&ctrl[4], 1u) == NBLK1 - 1) ? 1u : 0u;
  __syncthreads();
  if (!amLast) return;
  // ---- findcut1 (this block only) ----
  __threadfence();
  __shared__ uint32_t part[1024];
  int t = tid;
  uint4 s4 = make_uint4(0u, 0u, 0u, 0u);     // thread t owns bins 4t..4t+3
  const uint4* p4 = (const uint4*)part1;
  for (int k = 0; k < NBLK1; k++) {
    uint4 q = p4[k * 1024 + t];
    s4.x += q.x; s4.y += q.y; s4.z += q.z; s4.w += q.w;
  }
  uint32_t tot = s4.x + s4.y + s4.z + s4.w;
  part[t] = tot;
  __syncthreads();
  uint32_t inc = tot;
  for (int off = 1; off < 1024; off <<= 1) {
    uint32_t u = (t >= off) ? part[t - off] : 0u;
    __syncthreads();
    inc += u;
    part[t] = inc;
    __syncthreads();
  }
  uint32_t ex = inc - tot;
  if (ex < PRE_K && inc >= PRE_K) {
    uint32_t run = ex;
    uint32_t binv[4] = { s4.x, s4.y, s4.z, s4.w };
    for (int b = 0; b < 4; b++) {
      if (run + binv[b] >= PRE_K) { ctrl[2] = 4 * t + b; ctrl[3] = run; break; }
      run += binv[b];
    }
  }
  if (t == 1023 && inc < PRE_K) { ctrl[2] = 4095u; ctrl[3] = inc; }
}

// ---- K2: refine next 8 bits in coarse bin; last block finds T20 ----
__global__ void __launch_bounds__(1024) k_hist2(const uint32_t* __restrict__ keys,
                                                uint32_t* __restrict__ ctrl,
                                                uint32_t* __restrict__ part2) {
  __shared__ uint32_t lh[256];
  __shared__ uint32_t amLast;
  int tid = threadIdx.x;
  if (tid < 256) lh[tid] = 0u;
  __syncthreads();
  uint32_t c = ctrl[2];
  for (int i = blockIdx.x * 1024 + tid; i < N_ANCH; i += NBLK1 * 1024) {
    uint32_t k = keys[i];
    if ((k >> 20) == c) atomicAdd(&lh[(k >> 12) & 0xFFu], 1u);
  }
  __syncthreads();
  if (tid < 256) part2[blockIdx.x * 256 + tid] = lh[tid];
  __threadfence();
  if (tid == 0) amLast = (atomicAdd(&ctrl[5], 1u) == NBLK1 - 1) ? 1u : 0u;
  __syncthreads();
  if (!amLast) return;
  __threadfence();
  // ---- findcut2: single wave, lane owns 4 sub-bins ----
  if (tid < 64) {
    int lane = tid;
    uint32_t b0 = 0, b1 = 0, b2 = 0, b3 = 0;
    for (int k = 0; k < NBLK1; k++) {
      const uint32_t* p = part2 + k * 256 + 4 * lane;
      b0 += p[0]; b1 += p[1]; b2 += p[2]; b3 += p[3];
    }
    uint32_t tot = b0 + b1 + b2 + b3;
    uint32_t inc = wave_iscan(tot, lane);
    uint32_t base = ctrl[3];
    uint32_t ex = inc - tot;
    if (base + ex < PRE_K && base + inc >= PRE_K) {
      uint32_t run = base + ex;
      uint32_t binv[4] = { b0, b1, b2, b3 };
      for (int b = 0; b < 4; b++) {
        if (run + binv[b] >= PRE_K) { ctrl[1] = (c << 8) | (uint32_t)(4 * lane + b); break; }
        run += binv[b];
      }
    }
    if (lane == 63 && base + inc < PRE_K) ctrl[1] = 0xFFFFFu;  // take everything
  }
}

// ---- K3: compact candidates (key prefix <= T), wave-aggregated atomic ----
__global__ void k_compact(const uint32_t* __restrict__ keys,
                          const uint32_t* __restrict__ ctrl,
                          uint32_t* __restrict__ cnt,
                          uint64_t* __restrict__ cand) {
  int i = blockIdx.x * blockDim.x + threadIdx.x;
  uint32_t T = ctrl[1];
  bool pass = (i < N_ANCH) && ((keys[i] >> 12) <= T);
  uint64_t m = __ballot(pass);
  if (pass) {
    int lane = threadIdx.x & 63;
    int leader = __ffsll((unsigned long long)m) - 1;
    uint32_t base = 0;
    if (lane == leader) base = atomicAdd(cnt, (uint32_t)__popcll((unsigned long long)m));
    base = (uint32_t)__shfl((int)base, leader);
    uint32_t pos = (uint32_t)__popcll((unsigned long long)(m & ((1ull << lane) - 1ull)));
    uint32_t p = base + pos;
    if (p < NS) cand[p] = ((uint64_t)keys[i] << 20) | (uint32_t)i;  // 52-bit packed
  }
}

// ---- K4: single-block LSD radix sort (4-bit x 13) + gather/decode epilogue ----
__global__ void __launch_bounds__(1024) k_sortgather(
    const uint32_t* __restrict__ ctrl,
    const uint64_t* __restrict__ cand,
    const float4* __restrict__ anchors,
    const float4* __restrict__ deltas,
    float4* __restrict__ boxes,
    uint32_t* __restrict__ valid) {
  __shared__ uint64_t buf[NS];            // 56 KiB
  __shared__ uint32_t hist[16 * TILES];   // 7 KiB
  __shared__ uint32_t dtot[16];
  __shared__ uint32_t dbase[16];
  __shared__ uint32_t skipf;
  int tid = threadIdx.x;
  int wave = tid >> 6, lane = tid & 63;
  uint32_t M = ctrl[0]; if (M > NS) M = NS;
  uint32_t T = ctrl[1];
  uint64_t pad = (T >= 0xFFFFFu) ? 0xFFFFFFFFFFFFFull
                                 : ((((uint64_t)T + 1) << 32) | 0xFFFFFFFFull);
  for (int i = tid; i < NS; i += 1024)
    buf[i] = (i < (int)M) ? cand[i] : pad;
  __syncthreads();
  uint64_t lmask_lt = (1ull << lane) - 1ull;

  for (int p = 0; p < PASSES; p++) {
    int shift = 4 * p;
    for (int i = tid; i < 16 * TILES; i += 1024) hist[i] = 0u;
    uint64_t v[TPW]; int dg[TPW]; int rk[TPW];
    #pragma unroll
    for (int k = 0; k < TPW; k++)
      v[k] = buf[(wave * TPW + k) * 64 + lane];
    __syncthreads();
    #pragma unroll
    for (int k = 0; k < TPW; k++) {
      int d = (int)((v[k] >> shift) & 0xF);
      uint64_t m = ~0ull;
      #pragma unroll
      for (int b = 0; b < 4; b++) {
        uint64_t bal = __ballot((d >> b) & 1);
        m &= ((d >> b) & 1) ? bal : ~bal;
      }
      int r = (int)__popcll((unsigned long long)(m & lmask_lt));
      dg[k] = d; rk[k] = r;
      if (r == 0) hist[d * TILES + wave * TPW + k] = (uint32_t)__popcll((unsigned long long)m);
    }
    __syncthreads();
    {
      int d = wave;
      uint32_t c0 = hist[d * TILES + lane];
      uint32_t c1 = (lane < TILES - 64) ? hist[d * TILES + 64 + lane] : 0u;
      uint32_t s0 = wave_iscan(c0, lane);
      uint32_t T0 = (uint32_t)__shfl((int)s0, 63, 64);
      uint32_t s1 = wave_iscan(c1, lane);
      uint32_t T1 = (uint32_t)__shfl((int)s1, 63, 64);
      hist[d * TILES + lane] = s0 - c0;
      if (lane < TILES - 64) hist[d * TILES + 64 + lane] = T0 + (s1 - c1);
      if (lane == 0) dtot[d] = T0 + T1;
    }
    __syncthreads();
    if (wave == 0) {
      uint32_t x = (lane < 16) ? dtot[lane] : 0u;
      uint32_t xs = wave_iscan(x, lane);
      if (lane < 16) dbase[lane] = xs - x;
      if (lane == 0) skipf = 0u;
      if (lane < 16 && x == NS) skipf = 1u;
    }
    __syncthreads();
    if (!skipf) {
      #pragma unroll
      for (int k = 0; k < TPW; k++) {
        uint32_t dst = dbase[dg[k]] + hist[dg[k] * TILES + wave * TPW + k] + (uint32_t)rk[k];
        buf[dst] = v[k];
      }
    }
    __syncthreads();
  }

  for (int r = tid; r < ROWS; r += 1024) {
    if (r >= PRE_K) { boxes[r] = make_float4(0.f, 0.f, 0.f, 0.f); valid[r] = 0u; continue; }
    uint64_t kk = buf[r];
    uint32_t kd = (uint32_t)(kk >> 20);
    if (kk >= pad || kd >= 0xFF800000u) {
      boxes[r] = make_float4(0.f, 0.f, 0.f, 0.f); valid[r] = 0u; continue;
    }
    uint32_t idx = (uint32_t)(kk & 0xFFFFFu);
    float4 a = anchors[idx];
    float4 d = deltas[idx];
    float x1, y1, x2, y2; bool vv;
    decode_box(a.x, a.y, a.z, a.w, d.x, d.y, d.z, d.w, x1, y1, x2, y2, vv);
    boxes[r] = make_float4(x1, y1, x2, y2);
    valid[r] = 1u;
  }
}

// ---- K5: IoU bitmask matrix, row-major mask[row*WORDS + w] ----
__global__ void __launch_bounds__(64) k_iou(const float4* __restrict__ boxes,
                                            uint64_t* __restrict__ mask) {
  int by = blockIdx.y, bx = blockIdx.x;
  if (bx < by) return;               // only words w >= row's group are ever read
  __shared__ float4 cb[64];
  int t = threadIdx.x;
  cb[t] = boxes[bx * 64 + t];
  __syncthreads();
  int i = by * 64 + t;
  float4 b = boxes[i];
  float ax1 = b.x, ay1 = b.y, ax2 = b.z, ay2 = b.w;
  float areaA = __fmul_rn(__fsub_rn(ax2, ax1), __fsub_rn(ay2, ay1));
  uint64_t bits = 0;
  for (int c = 0; c < 64; c++) {
    float4 o = cb[c];
    float areaB = __fmul_rn(__fsub_rn(o.z, o.x), __fsub_rn(o.w, o.y));
    float ix1 = fmaxf(ax1, o.x), iy1 = fmaxf(ay1, o.y);
    float ix2 = fminf(ax2, o.z), iy2 = fminf(ay2, o.w);
    float iw = fmaxf(__fsub_rn(ix2, ix1), 0.0f);
    float ih = fmaxf(__fsub_rn(iy2, iy1), 0.0f);
    float inter = __fmul_rn(iw, ih);
    float uni = __fsub_rn(__fadd_rn(areaA, areaB), inter);
    bool sup = (uni > 0.0f) && (__fdiv_rn(inter, uni) > 0.7f);
    bits |= ((uint64_t)sup) << c;
  }
  mask[(size_t)i * WORDS + bx] = bits;
}

// wave-uniform 64-bit broadcast via v_readlane
__device__ __forceinline__ uint64_t bcast64(uint64_t v, int lane) {
  uint32_t lo = (uint32_t)__builtin_amdgcn_readlane((int)(uint32_t)v, lane);
  uint32_t hi = (uint32_t)__builtin_amdgcn_readlane((int)(uint32_t)(v >> 32), lane);
  return ((uint64_t)hi << 32) | lo;
}

// ---- K6: sequential NMS scan, single wave; SINGLE-DRAIN asm fold ----
// The fold batch is one inline-asm block: 32 global_load_dwordx2 issued
// back-to-back + s_waitcnt vmcnt(0) INSIDE the same asm, so there is exactly
// one memory drain per 16-row batch and the compiler cannot split it
// (R5/R6 showed the register allocator splits C-level batches into ~5
// load-wait-OR sub-batches at ~600cyc each).  w1 word = w0 word + 64
// -> reached via offset:512 on the same address (in-buffer for rows < 6000).
__global__ void __launch_bounds__(64, 1) k_nms(const uint64_t* __restrict__ mask,
                                               const float4* __restrict__ boxes,
                                               const uint32_t* __restrict__ valid,
                                               float* __restrict__ out) {
  __shared__ uint32_t list[1024];
  int lane = threadIdx.x;
  int w0 = lane, w1 = lane + 64;
  uint64_t r0 = 0, r1 = 0;           // removed-bit words: lane owns words w0, w1
  int cnt = 0;
  uint64_t colv = mask[(size_t)lane * WORDS + 0];     // prefetch group 0
  uint32_t vf = valid[lane];
  for (int g = 0; g < WORDS; g++) {
    int base = g * 64;
    uint64_t colv_c = colv;
    uint32_t vf_c = vf;
    if (g + 1 < WORDS) {                              // prefetch group g+1
      colv = mask[(size_t)(base + 64 + lane) * WORDS + (g + 1)];
      vf = valid[base + 64 + lane];
    }
    uint64_t cur = (g < 64) ? bcast64(r0, g) : bcast64(r1, g - 64);
    uint64_t vmask = __ballot(vf_c != 0u);
    uint64_t alive = vmask & ~cur;
    uint64_t keptmask = 0;
    while (alive) {                                   // serial decision chain
      int r = __ffsll((unsigned long long)alive) - 1;
      keptmask |= 1ull << r;
      if (lane == 0) list[cnt] = (uint32_t)(base + r);
      cnt++;
      if (cnt >= POST_K) break;
      uint64_t m = bcast64(colv_c, r);                // row r's in-group word
      alive &= ~m;
      alive &= ~(1ull << r);
    }
    if (cnt >= POST_K) break;
    // ---- single-drain fold: 16 rows per asm block (dup-padded, OR idempotent)
    uint64_t kml = keptmask;
    uint64_t acc0 = 0, acc1 = 0;
    while (kml) {
      int rp = __ffsll((unsigned long long)kml) - 1;  // pad row (dup of first)
      const uint64_t* a[16];
      #pragma unroll
      for (int i = 0; i < 16; i++) {
        int r = kml ? (__ffsll((unsigned long long)kml) - 1) : rp;
        a[i] = mask + (size_t)(base + r) * WORDS + w0;
        kml &= kml - 1;
      }
      uint64_t f0,f1,f2,f3,f4,f5,f6,f7,f8,f9,f10,f11,f12,f13,f14,f15;
      uint64_t h0,h1,h2,h3,h4,h5,h6,h7,h8,h9,h10,h11,h12,h13,h14,h15;
      asm volatile(
        "global_load_dwordx2 %0, %32, off\n\t"
        "global_load_dwordx2 %16, %32, off offset:512\n\t"
        "global_load_dwordx2 %1, %33, off\n\t"
        "global_load_dwordx2 %17, %33, off offset:512\n\t"
        "global_load_dwordx2 %2, %34, off\n\t"
        "global_load_dwordx2 %18, %34, off offset:512\n\t"
        "global_load_dwordx2 %3, %35, off\n\t"
        "global_load_dwordx2 %19, %35, off offset:512\n\t"
        "global_load_dwordx2 %4, %36, off\n\t"
        "global_load_dwordx2 %20, %36, off offset:512\n\t"
        "global_load_dwordx2 %5, %37, off\n\t"
        "global_load_dwordx2 %21, %37, off offset:512\n\t"
        "global_load_dwordx2 %6, %38, off\n\t"
        "global_load_dwordx2 %22, %38, off offset:512\n\t"
        "global_load_dwordx2 %7, %39, off\n\t"
        "global_load_dwordx2 %23, %39, off offset:512\n\t"
        "global_load_dwordx2 %8, %40, off\n\t"
        "global_load_dwordx2 %24, %40, off offset:512\n\t"
        "global_load_dwordx2 %9, %41, off\n\t"
        "global_load_dwordx2 %25, %41, off offset:512\n\t"
        "global_load_dwordx2 %10, %42, off\n\t"
        "global_load_dwordx2 %26, %42, off offset:512\n\t"
        "global_load_dwordx2 %11, %43, off\n\t"
        "global_load_dwordx2 %27, %43, off offset:512\n\t"
        "global_load_dwordx2 %12, %44, off\n\t"
        "global_load_dwordx2 %28, %44, off offset:512\n\t"
        "global_load_dwordx2 %13, %45, off\n\t"
        "global_load_dwordx2 %29, %45, off offset:512\n\t"
        "global_load_dwordx2 %14, %46, off\n\t"
        "global_load_dwordx2 %30, %46, off offset:512\n\t"
        "global_load_dwordx2 %15, %47, off\n\t"
        "global_load_dwordx2 %31, %47, off offset:512\n\t"
        "s_waitcnt vmcnt(0)"
        : "=&v"(f0), "=&v"(f1), "=&v"(f2), "=&v"(f3),
          "=&v"(f4), "=&v"(f5), "=&v"(f6), "=&v"(f7),
          "=&v"(f8), "=&v"(f9), "=&v"(f10), "=&v"(f11),
          "=&v"(f12), "=&v"(f13), "=&v"(f14), "=&v"(f15),
          "=&v"(h0), "=&v"(h1), "=&v"(h2), "=&v"(h3),
          "=&v"(h4), "=&v"(h5), "=&v"(h6), "=&v"(h7),
          "=&v"(h8), "=&v"(h9), "=&v"(h10), "=&v"(h11),
          "=&v"(h12), "=&v"(h13), "=&v"(h14), "=&v"(h15)
        : "v"(a[0]), "v"(a[1]), "v"(a[2]), "v"(a[3]),
          "v"(a[4]), "v"(a[5]), "v"(a[6]), "v"(a[7]),
          "v"(a[8]), "v"(a[9]), "v"(a[10]), "v"(a[11]),
          "v"(a[12]), "v"(a[13]), "v"(a[14]), "v"(a[15])
        : "memory");
      acc0 |= f0 | f1 | f2 | f3 | f4 | f5 | f6 | f7
            | f8 | f9 | f10 | f11 | f12 | f13 | f14 | f15;
      acc1 |= h0 | h1 | h2 | h3 | h4 | h5 | h6 | h7
            | h8 | h9 | h10 | h11 | h12 | h13 | h14 | h15;
    }
    if (w0 > g) r0 |= acc0;
    if (w1 > g && w1 < WORDS) r1 |= acc1;
  }
  __syncthreads();
  float4* outv = (float4*)out;
  for (int k = lane; k < POST_K; k += 64)
    outv[k] = (k < cnt) ? boxes[list[k]] : make_float4(0.f, 0.f, 0.f, 0.f);
}

extern "C" void kernel_launch(void* const* d_in, const int* in_sizes, int n_in,
                              void* d_out, int out_size, void* d_ws, size_t ws_size,
                              hipStream_t stream) {
  const float4* anchors = (const float4*)d_in[1];
  const float4* deltas  = (const float4*)d_in[2];
  const float*  logits  = (const float*)d_in[3];
  char* w = (char*)d_ws;
  uint32_t* keys  = (uint32_t*)(w + OFF_KEYS);
  uint32_t* part1 = (uint32_t*)(w + OFF_PART1);
  uint32_t* part2 = (uint32_t*)(w + OFF_PART2);
  uint32_t* ctrl  = (uint32_t*)(w + OFF_CTRL);
  uint64_t* cand  = (uint64_t*)(w + OFF_CAND);
  float4*   boxes = (float4*)(w + OFF_BOXES);
  uint32_t* valid = (uint32_t*)(w + OFF_VALID);
  uint64_t* mask  = (uint64_t*)(w + OFF_MASK);
  float*    out   = (float*)d_out;

  hipMemsetAsync(w + OFF_CTRL, 0, 256, stream);   // counters only

  k_score<<<NBLK1, 1024, 0, stream>>>(anchors, deltas, logits, keys, part1, ctrl);
  k_hist2<<<NBLK1, 1024, 0, stream>>>(keys, ctrl, part2);
  k_compact<<<(N_ANCH + 255) / 256, 256, 0, stream>>>(keys, ctrl, &ctrl[0], cand);
  k_sortgather<<<1, 1024, 0, stream>>>(ctrl, cand, anchors, deltas, boxes, valid);
  k_iou<<<dim3(WORDS, WORDS), 64, 0, stream>>>(boxes, mask);
  k_nms<<<1, 64, 0, stream>>>(mask, boxes, valid, out);
}